// Round 4
// baseline (269.974 us; speedup 1.0000x reference)
//
#include <hip/hip_runtime.h>

// ---------------------------------------------------------------------------
// MultilevelSelfAttentionBlockWithRoPE on MI355X (gfx950)
// LN -> (W transpose->bf16) -> QKV GEMM (bf16 MFMA) -> RoPE -> flash
// attention -> out GEMM + residual.
// R4: attn = 2-wave blocks (128 thr), 64 q/block, 32 q/wave (2 qi).
// Rationale: R3 counters showed LDS pipe ~73% busy (K/V frags re-read by 4
// waves for 16q each); 2qi halves LDS reads per q-row while keeping the
// 2048-block grid for block-level parallelism.
// ---------------------------------------------------------------------------

typedef float  f32x4  __attribute__((ext_vector_type(4)));
typedef __bf16 bf16x8 __attribute__((ext_vector_type(8)));
typedef __bf16 bf16x4 __attribute__((ext_vector_type(4)));
typedef short  s16x4  __attribute__((ext_vector_type(4)));
typedef short  s16x8  __attribute__((ext_vector_type(8)));
typedef unsigned short u16x4 __attribute__((ext_vector_type(4)));

typedef __attribute__((address_space(1))) void as1_void_t;
typedef __attribute__((address_space(3))) void as3_void_t;

static __device__ __forceinline__ unsigned short f2bf(float f) {
  unsigned int u = __float_as_uint(f);
  u += 0x7fffu + ((u >> 16) & 1u);          // round-to-nearest-even
  return (unsigned short)(u >> 16);
}
static __device__ __forceinline__ float bf2f(unsigned short s) {
  return __uint_as_float(((unsigned int)s) << 16);
}

static __device__ __forceinline__ void gload_lds16(const void* g, void* l) {
  __builtin_amdgcn_global_load_lds((as1_void_t*)g, (as3_void_t*)l, 16, 0, 0);
}

static __device__ __forceinline__ f32x4 mfma32(bf16x8 a, bf16x8 b, f32x4 c) {
  return __builtin_amdgcn_mfma_f32_16x16x32_bf16(a, b, c, 0, 0, 0);
}
static __device__ __forceinline__ f32x4 mfma16(s16x4 a, s16x4 b, f32x4 c) {
  return __builtin_amdgcn_mfma_f32_16x16x16bf16_1k(a, b, c, 0, 0, 0);
}

// ---------------------------------------------------------------------------
// LayerNorm: x f32 [N][1024] -> h bf16 [N][1024].  One wave per row.
// ---------------------------------------------------------------------------
__global__ __launch_bounds__(256) void ln_kernel(
    const float* __restrict__ x, const float* __restrict__ gamma,
    const float* __restrict__ beta, unsigned short* __restrict__ h, int Ntok) {
  int row  = blockIdx.x * 4 + (threadIdx.x >> 6);
  int lane = threadIdx.x & 63;
  const float* xr = x + (size_t)row * 1024;
  f32x4 v[4];
  float s = 0.f, ss = 0.f;
#pragma unroll
  for (int c = 0; c < 4; ++c) {
    v[c] = *(const f32x4*)(xr + c * 256 + lane * 4);
#pragma unroll
    for (int j = 0; j < 4; ++j) { s += v[c][j]; ss += v[c][j] * v[c][j]; }
  }
#pragma unroll
  for (int d = 1; d < 64; d <<= 1) {
    s  += __shfl_xor(s, d);
    ss += __shfl_xor(ss, d);
  }
  float mu  = s * (1.f / 1024.f);
  float var = ss * (1.f / 1024.f) - mu * mu;
  float inv = rsqrtf(var + 1e-5f);
#pragma unroll
  for (int c = 0; c < 4; ++c) {
    f32x4 gv = *(const f32x4*)(gamma + c * 256 + lane * 4);
    f32x4 bv = *(const f32x4*)(beta  + c * 256 + lane * 4);
    u16x4 hv;
#pragma unroll
    for (int j = 0; j < 4; ++j) hv[j] = f2bf((v[c][j] - mu) * inv * gv[j] + bv[j]);
    *(u16x4*)(h + (size_t)row * 1024 + c * 256 + lane * 4) = hv;
  }
}

// ---------------------------------------------------------------------------
// Transpose+convert: in f32 [R][C] -> out bf16 [C][R]
// ---------------------------------------------------------------------------
__global__ __launch_bounds__(256) void transpose_bf16(
    const float* __restrict__ in, unsigned short* __restrict__ out, int R, int C) {
  __shared__ unsigned short tile[64][65];
  int c0 = blockIdx.x * 64, r0 = blockIdx.y * 64;
  int t = threadIdx.x;
  int tr = t >> 6, tc = t & 63;
#pragma unroll
  for (int i = 0; i < 16; ++i) {
    int rr = i * 4 + tr;
    tile[tc][rr] = f2bf(in[(size_t)(r0 + rr) * C + c0 + tc]);
  }
  __syncthreads();
#pragma unroll
  for (int i = 0; i < 16; ++i) {
    int cc = i * 4 + tr;
    out[(size_t)(c0 + cc) * R + r0 + tc] = tile[cc][tc];
  }
}

// ---------------------------------------------------------------------------
// GEMM  C[M][Ncols] = A[M][K](bf16) * Bt[Ncols][K](bf16)^T
// MODE 0: Cf = acc + residual (f32 out)
// MODE 1: scatter bf16 into QKV planes [3][16][M][64]
// ---------------------------------------------------------------------------
template <int MODE>
__global__ __launch_bounds__(256) void gemm_bt(
    const unsigned short* __restrict__ A, const unsigned short* __restrict__ Bt,
    const float* __restrict__ residual, float* __restrict__ Cf,
    unsigned short* __restrict__ Cqkv, int M, int Ncols, int K) {
  __shared__ unsigned short Alds[128 * 32];
  __shared__ unsigned short Blds[128 * 32];
  int n0 = blockIdx.x * 128, m0 = blockIdx.y * 128;
  int t = threadIdx.x, lane = t & 63, wave = t >> 6;
  int wr = wave >> 1, wc = wave & 1;
  int r = lane & 15, g = lane >> 4;
  f32x4 acc[4][4] = {};

  int srow = lane >> 2;
  int scol = (lane & 3) * 8;

  for (int k0 = 0; k0 < K; k0 += 32) {
    __syncthreads();
#pragma unroll
    for (int c = 0; c < 2; ++c) {
      int seg = wave * 2 + c;
      gload_lds16(A  + (size_t)(m0 + seg * 16 + srow) * K + k0 + scol,
                  Alds + seg * 16 * 32);
      gload_lds16(Bt + (size_t)(n0 + seg * 16 + srow) * K + k0 + scol,
                  Blds + seg * 16 * 32);
    }
    __syncthreads();
    bf16x8 a[4], b[4];
#pragma unroll
    for (int m = 0; m < 4; ++m)
      a[m] = *(const bf16x8*)(Alds + (wr * 64 + m * 16 + r) * 32 + g * 8);
#pragma unroll
    for (int n = 0; n < 4; ++n)
      b[n] = *(const bf16x8*)(Blds + (wc * 64 + n * 16 + r) * 32 + g * 8);
#pragma unroll
    for (int m = 0; m < 4; ++m)
#pragma unroll
      for (int n = 0; n < 4; ++n)
        acc[m][n] = mfma32(a[m], b[n], acc[m][n]);
  }

#pragma unroll
  for (int mi = 0; mi < 4; ++mi) {
    int grow0 = m0 + wr * 64 + mi * 16 + g * 4;
#pragma unroll
    for (int ni = 0; ni < 4; ++ni) {
      int gcol = n0 + wc * 64 + ni * 16 + r;
      f32x4 v = acc[mi][ni];
#pragma unroll
      for (int e = 0; e < 4; ++e) {
        int grow = grow0 + e;
        if (MODE == 0) {
          Cf[(size_t)grow * Ncols + gcol] =
              v[e] + residual[(size_t)grow * Ncols + gcol];
        } else {
          int which = gcol >> 10, rem = gcol & 1023, hh = rem >> 6, d = rem & 63;
          Cqkv[((size_t)(which * 16 + hh) * M + grow) * 64 + d] = f2bf(v[e]);
        }
      }
    }
  }
}

// ---------------------------------------------------------------------------
// RoPE in place on Q,K planes of QKV [3][16][N][64] bf16.
// ---------------------------------------------------------------------------
__global__ __launch_bounds__(256) void rope_kernel(
    unsigned short* __restrict__ QKV, const float* __restrict__ pos,
    const float* __restrict__ freqs, int Ntok) {
  int t = blockIdx.x * 256 + threadIdx.x;
  if (t >= Ntok * 512) return;
  int kk = t & 31, h = (t >> 5) & 15, i = t >> 9;
  float lvlf = pos[i * 3 + 0];
  float py   = pos[i * 3 + 1];
  float px   = pos[i * 3 + 2];
  int lvl = (int)lvlf;
  lvl = lvl < 0 ? 0 : (lvl > 3 ? 3 : lvl);
  const float* fp = freqs + (((lvl * 16 + h) * 32 + kk) << 1);
  float ang = fp[0] * py + fp[1] * px;
  float s, c;
  __sincosf(ang, &s, &c);
  size_t qoff = ((size_t)h * Ntok + i) * 64 + 2 * kk;
  size_t koff = qoff + (size_t)16 * Ntok * 64;
  unsigned int q2 = *(const unsigned int*)(QKV + qoff);
  float qa = bf2f((unsigned short)(q2 & 0xffff));
  float qb = bf2f((unsigned short)(q2 >> 16));
  *(unsigned int*)(QKV + qoff) =
      (unsigned int)f2bf(qa * c - qb * s) | ((unsigned int)f2bf(qa * s + qb * c) << 16);
  unsigned int k2 = *(const unsigned int*)(QKV + koff);
  float ka = bf2f((unsigned short)(k2 & 0xffff));
  float kb = bf2f((unsigned short)(k2 >> 16));
  *(unsigned int*)(QKV + koff) =
      (unsigned int)f2bf(ka * c - kb * s) | ((unsigned int)f2bf(ka * s + kb * c) << 16);
}

// ---------------------------------------------------------------------------
// Flash attention.  Block = (batch, head, 64 q rows); 2 waves x 32 q rows
// (2 qi of 16).  S^T = K*Q^T (mfma 16x16x32); per-64-key-tile online softmax
// (log2 domain, defer-max); V transposed in LDS (PV B-frags = ds_read_b64,
// reused across qi); reg-staged single-LDS-buffer pipeline; XCD swizzle.
// ---------------------------------------------------------------------------
__global__ __launch_bounds__(128, 4) void attn_kernel(
    const unsigned short* __restrict__ QKV, const int* __restrict__ boff,
    unsigned short* __restrict__ O, int Ntok) {
  __shared__ unsigned short Klds[64][72];
  __shared__ unsigned short Vt[64][72];   // Vt[d][key]
  const float SCALE_LOG2 = 0.125f * 1.44269504088896340736f;

  int nb  = gridDim.x;
  int bid = blockIdx.x;
  int cpx = nb >> 3;                       // nb % 8 == 0 (2048)
  int blk = (bid & 7) * cpx + (bid >> 3);  // XCD-contiguous work chunks
  int qblk = blk & 15, h = (blk >> 4) & 15, b = blk >> 8;
  int off = boff[b], len = boff[b + 1] - off;
  int q0 = qblk * 64;
  if (q0 >= len) return;
  int t = threadIdx.x, lane = t & 63, wave = t >> 6;
  int r = lane & 15, g = lane >> 4;
  const unsigned short* Qg = QKV + (size_t)h * Ntok * 64;
  const unsigned short* Kg = QKV + (size_t)(16 + h) * Ntok * 64;
  const unsigned short* Vg = QKV + (size_t)(32 + h) * Ntok * 64;
  int qmax = off + len - 1;

  bf16x8 qf[2][2];
#pragma unroll
  for (int qi = 0; qi < 2; ++qi) {
    int qtok = off + q0 + wave * 32 + qi * 16 + r;
    if (qtok > qmax) qtok = qmax;
#pragma unroll
    for (int c = 0; c < 2; ++c)
      qf[qi][c] = *(const bf16x8*)(Qg + (size_t)qtok * 64 + c * 32 + g * 8);
  }

  float m[2] = {-1e30f, -1e30f}, lsum[2] = {0.f, 0.f};
  f32x4 o[2][4] = {};

  // staging assignments (128 threads)
  int krow = t >> 1, kseg = t & 1;   // K: key=krow, shorts [kseg*32, +32)
  int vp = t & 31, vdc = t >> 5;     // V: keys 2vp,2vp+1, d = vdc*16..+15

  s16x8 kr[4], va0, va1, vb0, vb1;
  {
    int ktok = off + krow; if (ktok > qmax) ktok = qmax;
#pragma unroll
    for (int c = 0; c < 4; ++c)
      kr[c] = *(const s16x8*)(Kg + (size_t)ktok * 64 + kseg * 32 + c * 8);
    int va = off + 2 * vp, vb = va + 1;
    if (va > qmax) va = qmax;
    if (vb > qmax) vb = qmax;
    va0 = *(const s16x8*)(Vg + (size_t)va * 64 + vdc * 16);
    va1 = *(const s16x8*)(Vg + (size_t)va * 64 + vdc * 16 + 8);
    vb0 = *(const s16x8*)(Vg + (size_t)vb * 64 + vdc * 16);
    vb1 = *(const s16x8*)(Vg + (size_t)vb * 64 + vdc * 16 + 8);
  }

  for (int kt = 0; kt < len; kt += 64) {
    __syncthreads();                       // previous tile's compute done
#pragma unroll
    for (int c = 0; c < 4; ++c)
      *(s16x8*)&Klds[krow][kseg * 32 + c * 8] = kr[c];
#pragma unroll
    for (int j = 0; j < 8; ++j) {
      unsigned int p0 = (unsigned int)(unsigned short)va0[j] |
                        ((unsigned int)(unsigned short)vb0[j] << 16);
      unsigned int p1 = (unsigned int)(unsigned short)va1[j] |
                        ((unsigned int)(unsigned short)vb1[j] << 16);
      *(unsigned int*)&Vt[vdc * 16 + j][2 * vp]     = p0;
      *(unsigned int*)&Vt[vdc * 16 + 8 + j][2 * vp] = p1;
    }
    int ktn = kt + 64;
    if (ktn < len) {                       // prefetch next tile into regs
      int ktok = off + ktn + krow; if (ktok > qmax) ktok = qmax;
#pragma unroll
      for (int c = 0; c < 4; ++c)
        kr[c] = *(const s16x8*)(Kg + (size_t)ktok * 64 + kseg * 32 + c * 8);
      int va = off + ktn + 2 * vp, vb = va + 1;
      if (va > qmax) va = qmax;
      if (vb > qmax) vb = qmax;
      va0 = *(const s16x8*)(Vg + (size_t)va * 64 + vdc * 16);
      va1 = *(const s16x8*)(Vg + (size_t)va * 64 + vdc * 16 + 8);
      vb0 = *(const s16x8*)(Vg + (size_t)vb * 64 + vdc * 16);
      vb1 = *(const s16x8*)(Vg + (size_t)vb * 64 + vdc * 16 + 8);
    }
    __syncthreads();                       // LDS tile ready

    // ---- scores: S^T[key][q] for 64 keys x 32 q rows -------------------
    f32x4 s[2][4];
#pragma unroll
    for (int sub = 0; sub < 4; ++sub) {
      bf16x8 ka0 = *(const bf16x8*)(&Klds[sub * 16 + r][g * 8]);
      bf16x8 ka1 = *(const bf16x8*)(&Klds[sub * 16 + r][32 + g * 8]);
#pragma unroll
      for (int qi = 0; qi < 2; ++qi) {
        f32x4 acc = {};
        acc = mfma32(ka0, qf[qi][0], acc);
        acc = mfma32(ka1, qf[qi][1], acc);
        s[qi][sub] = acc;
      }
    }

    bool tail = (kt + 64 > len);
    s16x4 pf[2][4];
#pragma unroll
    for (int qi = 0; qi < 2; ++qi) {
      float sc[4][4];
      float tmax = -1e30f;
#pragma unroll
      for (int sub = 0; sub < 4; ++sub)
#pragma unroll
        for (int e = 0; e < 4; ++e) {
          float v = s[qi][sub][e] * SCALE_LOG2;
          sc[sub][e] = v;
          tmax = fmaxf(tmax, v);
        }
      if (tail) {
#pragma unroll
        for (int sub = 0; sub < 4; ++sub)
#pragma unroll
          for (int e = 0; e < 4; ++e)
            if (kt + sub * 16 + 4 * g + e >= len) sc[sub][e] = -1e30f;
        tmax = -1e30f;
#pragma unroll
        for (int sub = 0; sub < 4; ++sub)
#pragma unroll
          for (int e = 0; e < 4; ++e) tmax = fmaxf(tmax, sc[sub][e]);
      }
      tmax = fmaxf(tmax, __shfl_xor(tmax, 16));
      tmax = fmaxf(tmax, __shfl_xor(tmax, 32));
      float mq = m[qi];
      if (!__all(tmax <= mq + 8.f)) {      // defer-max (log2 domain)
        float mnew = fmaxf(mq, tmax);
        float alpha = exp2f(mq - mnew);
        lsum[qi] *= alpha;
        m[qi] = mnew; mq = mnew;
        float al[4];
#pragma unroll
        for (int e = 0; e < 4; ++e) al[e] = __shfl(alpha, 4 * g + e);
#pragma unroll
        for (int dt = 0; dt < 4; ++dt)
#pragma unroll
          for (int e = 0; e < 4; ++e) o[qi][dt][e] *= al[e];
      }
      float psum = 0.f;
#pragma unroll
      for (int sub = 0; sub < 4; ++sub) {
        float p[4];
        bf16x4 pb;
#pragma unroll
        for (int e = 0; e < 4; ++e) {
          p[e] = exp2f(sc[sub][e] - mq);
          psum += p[e];
          pb[e] = (__bf16)p[e];
        }
        pf[qi][sub] = __builtin_bit_cast(s16x4, pb);
      }
      psum += __shfl_xor(psum, 16);
      psum += __shfl_xor(psum, 32);
      lsum[qi] += psum;
    }

    // ---- PV: O += P * V  (V^T frags b64, reused across qi) --------------
#pragma unroll
    for (int dt = 0; dt < 4; ++dt)
#pragma unroll
      for (int sub = 0; sub < 4; ++sub) {
        s16x4 vf = *(const s16x4*)(&Vt[dt * 16 + r][sub * 16 + 4 * g]);
#pragma unroll
        for (int qi = 0; qi < 2; ++qi)
          o[qi][dt] = mfma16(pf[qi][sub], vf, o[qi][dt]);
      }
  }

#pragma unroll
  for (int qi = 0; qi < 2; ++qi) {
    float inv = 1.0f / lsum[qi];
    float il[4];
#pragma unroll
    for (int e = 0; e < 4; ++e) il[e] = __shfl(inv, 4 * g + e);
#pragma unroll
    for (int dt = 0; dt < 4; ++dt)
#pragma unroll
      for (int e = 0; e < 4; ++e) {
        int tl = q0 + wave * 32 + qi * 16 + 4 * g + e;
        if (tl < len)
          O[(size_t)(off + tl) * 1024 + h * 64 + dt * 16 + r] =
              f2bf(o[qi][dt][e] * il[e]);
      }
  }
}

// ---------------------------------------------------------------------------
extern "C" void kernel_launch(void* const* d_in, const int* in_sizes, int n_in,
                              void* d_out, int out_size, void* d_ws, size_t ws_size,
                              hipStream_t stream) {
  const float* x     = (const float*)d_in[0];
  const float* pos   = (const float*)d_in[1];
  const int*   boff  = (const int*)d_in[2];
  const float* gamma = (const float*)d_in[3];
  const float* beta  = (const float*)d_in[4];
  const float* wqkv  = (const float*)d_in[5];
  const float* wout  = (const float*)d_in[6];
  const float* freqs = (const float*)d_in[7];
  float* out = (float*)d_out;
  int N  = in_sizes[0] / 1024;   // 6144
  int Bn = in_sizes[2] - 1;      // 8

  char* ws = (char*)d_ws;
  unsigned short* wqkvT = (unsigned short*)ws;
  unsigned short* woutT = (unsigned short*)(ws + (size_t)3072 * 1024 * 2);
  unsigned short* QKV   = (unsigned short*)(ws + (size_t)3072 * 1024 * 2 +
                                            (size_t)1024 * 1024 * 2);
  size_t qkvBytes = (size_t)48 * N * 64 * 2;
  unsigned short* hbuf = (unsigned short*)((char*)QKV + qkvBytes);
  unsigned short* Obuf = hbuf;  // h is dead after the QKV GEMM

  ln_kernel<<<N / 4, 256, 0, stream>>>(x, gamma, beta, hbuf, N);
  transpose_bf16<<<dim3(3072 / 64, 1024 / 64), 256, 0, stream>>>(wqkv, wqkvT, 1024, 3072);
  transpose_bf16<<<dim3(1024 / 64, 1024 / 64), 256, 0, stream>>>(wout, woutT, 1024, 1024);
  gemm_bt<1><<<dim3(3072 / 128, N / 128), 256, 0, stream>>>(
      hbuf, wqkvT, nullptr, nullptr, QKV, N, 3072, 1024);
  rope_kernel<<<(N * 512) / 256, 256, 0, stream>>>(QKV, pos, freqs, N);
  attn_kernel<<<Bn * 16 * 16, 128, 0, stream>>>(QKV, boff, Obuf, N);
  gemm_bt<0><<<dim3(1024 / 128, N / 128), 256, 0, stream>>>(
      Obuf, woutT, x, out, nullptr, N, 1024, 1024);
}

// Round 5
// 216.843 us; speedup vs baseline: 1.2450x; 1.2450x over previous
//
#include <hip/hip_runtime.h>

// ---------------------------------------------------------------------------
// MultilevelSelfAttentionBlockWithRoPE on MI355X (gfx950)
// LN -> (W transpose->bf16) -> QKV GEMM (bf16 MFMA) -> RoPE -> flash
// attention -> out GEMM + residual.
// R5: identical to R4 except attn launch bounds (128,4)->(128,3).
// R4 post-mortem: (128,4) capped unified VGPR+AGPR at 128 -> compiler split
// 64 arch + acc and spilled ~40 regs -> 178 MB scratch WRITE_SIZE, 168 us.
// (128,3) caps at ~170, kernel needs ~110-120 -> no spill, still 4 waves/SIMD.
// ---------------------------------------------------------------------------

typedef float  f32x4  __attribute__((ext_vector_type(4)));
typedef __bf16 bf16x8 __attribute__((ext_vector_type(8)));
typedef __bf16 bf16x4 __attribute__((ext_vector_type(4)));
typedef short  s16x4  __attribute__((ext_vector_type(4)));
typedef short  s16x8  __attribute__((ext_vector_type(8)));
typedef unsigned short u16x4 __attribute__((ext_vector_type(4)));

typedef __attribute__((address_space(1))) void as1_void_t;
typedef __attribute__((address_space(3))) void as3_void_t;

static __device__ __forceinline__ unsigned short f2bf(float f) {
  unsigned int u = __float_as_uint(f);
  u += 0x7fffu + ((u >> 16) & 1u);          // round-to-nearest-even
  return (unsigned short)(u >> 16);
}
static __device__ __forceinline__ float bf2f(unsigned short s) {
  return __uint_as_float(((unsigned int)s) << 16);
}

static __device__ __forceinline__ void gload_lds16(const void* g, void* l) {
  __builtin_amdgcn_global_load_lds((as1_void_t*)g, (as3_void_t*)l, 16, 0, 0);
}

static __device__ __forceinline__ f32x4 mfma32(bf16x8 a, bf16x8 b, f32x4 c) {
  return __builtin_amdgcn_mfma_f32_16x16x32_bf16(a, b, c, 0, 0, 0);
}
static __device__ __forceinline__ f32x4 mfma16(s16x4 a, s16x4 b, f32x4 c) {
  return __builtin_amdgcn_mfma_f32_16x16x16bf16_1k(a, b, c, 0, 0, 0);
}

// ---------------------------------------------------------------------------
// LayerNorm: x f32 [N][1024] -> h bf16 [N][1024].  One wave per row.
// ---------------------------------------------------------------------------
__global__ __launch_bounds__(256) void ln_kernel(
    const float* __restrict__ x, const float* __restrict__ gamma,
    const float* __restrict__ beta, unsigned short* __restrict__ h, int Ntok) {
  int row  = blockIdx.x * 4 + (threadIdx.x >> 6);
  int lane = threadIdx.x & 63;
  const float* xr = x + (size_t)row * 1024;
  f32x4 v[4];
  float s = 0.f, ss = 0.f;
#pragma unroll
  for (int c = 0; c < 4; ++c) {
    v[c] = *(const f32x4*)(xr + c * 256 + lane * 4);
#pragma unroll
    for (int j = 0; j < 4; ++j) { s += v[c][j]; ss += v[c][j] * v[c][j]; }
  }
#pragma unroll
  for (int d = 1; d < 64; d <<= 1) {
    s  += __shfl_xor(s, d);
    ss += __shfl_xor(ss, d);
  }
  float mu  = s * (1.f / 1024.f);
  float var = ss * (1.f / 1024.f) - mu * mu;
  float inv = rsqrtf(var + 1e-5f);
#pragma unroll
  for (int c = 0; c < 4; ++c) {
    f32x4 gv = *(const f32x4*)(gamma + c * 256 + lane * 4);
    f32x4 bv = *(const f32x4*)(beta  + c * 256 + lane * 4);
    u16x4 hv;
#pragma unroll
    for (int j = 0; j < 4; ++j) hv[j] = f2bf((v[c][j] - mu) * inv * gv[j] + bv[j]);
    *(u16x4*)(h + (size_t)row * 1024 + c * 256 + lane * 4) = hv;
  }
}

// ---------------------------------------------------------------------------
// Transpose+convert: in f32 [R][C] -> out bf16 [C][R]
// ---------------------------------------------------------------------------
__global__ __launch_bounds__(256) void transpose_bf16(
    const float* __restrict__ in, unsigned short* __restrict__ out, int R, int C) {
  __shared__ unsigned short tile[64][65];
  int c0 = blockIdx.x * 64, r0 = blockIdx.y * 64;
  int t = threadIdx.x;
  int tr = t >> 6, tc = t & 63;
#pragma unroll
  for (int i = 0; i < 16; ++i) {
    int rr = i * 4 + tr;
    tile[tc][rr] = f2bf(in[(size_t)(r0 + rr) * C + c0 + tc]);
  }
  __syncthreads();
#pragma unroll
  for (int i = 0; i < 16; ++i) {
    int cc = i * 4 + tr;
    out[(size_t)(c0 + cc) * R + r0 + tc] = tile[cc][tc];
  }
}

// ---------------------------------------------------------------------------
// GEMM  C[M][Ncols] = A[M][K](bf16) * Bt[Ncols][K](bf16)^T
// MODE 0: Cf = acc + residual (f32 out)
// MODE 1: scatter bf16 into QKV planes [3][16][M][64]
// ---------------------------------------------------------------------------
template <int MODE>
__global__ __launch_bounds__(256) void gemm_bt(
    const unsigned short* __restrict__ A, const unsigned short* __restrict__ Bt,
    const float* __restrict__ residual, float* __restrict__ Cf,
    unsigned short* __restrict__ Cqkv, int M, int Ncols, int K) {
  __shared__ unsigned short Alds[128 * 32];
  __shared__ unsigned short Blds[128 * 32];
  int n0 = blockIdx.x * 128, m0 = blockIdx.y * 128;
  int t = threadIdx.x, lane = t & 63, wave = t >> 6;
  int wr = wave >> 1, wc = wave & 1;
  int r = lane & 15, g = lane >> 4;
  f32x4 acc[4][4] = {};

  int srow = lane >> 2;
  int scol = (lane & 3) * 8;

  for (int k0 = 0; k0 < K; k0 += 32) {
    __syncthreads();
#pragma unroll
    for (int c = 0; c < 2; ++c) {
      int seg = wave * 2 + c;
      gload_lds16(A  + (size_t)(m0 + seg * 16 + srow) * K + k0 + scol,
                  Alds + seg * 16 * 32);
      gload_lds16(Bt + (size_t)(n0 + seg * 16 + srow) * K + k0 + scol,
                  Blds + seg * 16 * 32);
    }
    __syncthreads();
    bf16x8 a[4], b[4];
#pragma unroll
    for (int m = 0; m < 4; ++m)
      a[m] = *(const bf16x8*)(Alds + (wr * 64 + m * 16 + r) * 32 + g * 8);
#pragma unroll
    for (int n = 0; n < 4; ++n)
      b[n] = *(const bf16x8*)(Blds + (wc * 64 + n * 16 + r) * 32 + g * 8);
#pragma unroll
    for (int m = 0; m < 4; ++m)
#pragma unroll
      for (int n = 0; n < 4; ++n)
        acc[m][n] = mfma32(a[m], b[n], acc[m][n]);
  }

#pragma unroll
  for (int mi = 0; mi < 4; ++mi) {
    int grow0 = m0 + wr * 64 + mi * 16 + g * 4;
#pragma unroll
    for (int ni = 0; ni < 4; ++ni) {
      int gcol = n0 + wc * 64 + ni * 16 + r;
      f32x4 v = acc[mi][ni];
#pragma unroll
      for (int e = 0; e < 4; ++e) {
        int grow = grow0 + e;
        if (MODE == 0) {
          Cf[(size_t)grow * Ncols + gcol] =
              v[e] + residual[(size_t)grow * Ncols + gcol];
        } else {
          int which = gcol >> 10, rem = gcol & 1023, hh = rem >> 6, d = rem & 63;
          Cqkv[((size_t)(which * 16 + hh) * M + grow) * 64 + d] = f2bf(v[e]);
        }
      }
    }
  }
}

// ---------------------------------------------------------------------------
// RoPE in place on Q,K planes of QKV [3][16][N][64] bf16.
// ---------------------------------------------------------------------------
__global__ __launch_bounds__(256) void rope_kernel(
    unsigned short* __restrict__ QKV, const float* __restrict__ pos,
    const float* __restrict__ freqs, int Ntok) {
  int t = blockIdx.x * 256 + threadIdx.x;
  if (t >= Ntok * 512) return;
  int kk = t & 31, h = (t >> 5) & 15, i = t >> 9;
  float lvlf = pos[i * 3 + 0];
  float py   = pos[i * 3 + 1];
  float px   = pos[i * 3 + 2];
  int lvl = (int)lvlf;
  lvl = lvl < 0 ? 0 : (lvl > 3 ? 3 : lvl);
  const float* fp = freqs + (((lvl * 16 + h) * 32 + kk) << 1);
  float ang = fp[0] * py + fp[1] * px;
  float s, c;
  __sincosf(ang, &s, &c);
  size_t qoff = ((size_t)h * Ntok + i) * 64 + 2 * kk;
  size_t koff = qoff + (size_t)16 * Ntok * 64;
  unsigned int q2 = *(const unsigned int*)(QKV + qoff);
  float qa = bf2f((unsigned short)(q2 & 0xffff));
  float qb = bf2f((unsigned short)(q2 >> 16));
  *(unsigned int*)(QKV + qoff) =
      (unsigned int)f2bf(qa * c - qb * s) | ((unsigned int)f2bf(qa * s + qb * c) << 16);
  unsigned int k2 = *(const unsigned int*)(QKV + koff);
  float ka = bf2f((unsigned short)(k2 & 0xffff));
  float kb = bf2f((unsigned short)(k2 >> 16));
  *(unsigned int*)(QKV + koff) =
      (unsigned int)f2bf(ka * c - kb * s) | ((unsigned int)f2bf(ka * s + kb * c) << 16);
}

// ---------------------------------------------------------------------------
// Flash attention.  Block = (batch, head, 64 q rows); 2 waves x 32 q rows
// (2 qi of 16).  S^T = K*Q^T (mfma 16x16x32); per-64-key-tile online softmax
// (log2 domain, defer-max); V transposed in LDS (PV B-frags = ds_read_b64,
// reused across qi); reg-staged single-LDS-buffer pipeline; XCD swizzle.
// ---------------------------------------------------------------------------
__global__ __launch_bounds__(128, 3) void attn_kernel(
    const unsigned short* __restrict__ QKV, const int* __restrict__ boff,
    unsigned short* __restrict__ O, int Ntok) {
  __shared__ unsigned short Klds[64][72];
  __shared__ unsigned short Vt[64][72];   // Vt[d][key]
  const float SCALE_LOG2 = 0.125f * 1.44269504088896340736f;

  int nb  = gridDim.x;
  int bid = blockIdx.x;
  int cpx = nb >> 3;                       // nb % 8 == 0 (2048)
  int blk = (bid & 7) * cpx + (bid >> 3);  // XCD-contiguous work chunks
  int qblk = blk & 15, h = (blk >> 4) & 15, b = blk >> 8;
  int off = boff[b], len = boff[b + 1] - off;
  int q0 = qblk * 64;
  if (q0 >= len) return;
  int t = threadIdx.x, lane = t & 63, wave = t >> 6;
  int r = lane & 15, g = lane >> 4;
  const unsigned short* Qg = QKV + (size_t)h * Ntok * 64;
  const unsigned short* Kg = QKV + (size_t)(16 + h) * Ntok * 64;
  const unsigned short* Vg = QKV + (size_t)(32 + h) * Ntok * 64;
  int qmax = off + len - 1;

  bf16x8 qf[2][2];
#pragma unroll
  for (int qi = 0; qi < 2; ++qi) {
    int qtok = off + q0 + wave * 32 + qi * 16 + r;
    if (qtok > qmax) qtok = qmax;
#pragma unroll
    for (int c = 0; c < 2; ++c)
      qf[qi][c] = *(const bf16x8*)(Qg + (size_t)qtok * 64 + c * 32 + g * 8);
  }

  float m[2] = {-1e30f, -1e30f}, lsum[2] = {0.f, 0.f};
  f32x4 o[2][4] = {};

  // staging assignments (128 threads)
  int krow = t >> 1, kseg = t & 1;   // K: key=krow, shorts [kseg*32, +32)
  int vp = t & 31, vdc = t >> 5;     // V: keys 2vp,2vp+1, d = vdc*16..+15

  s16x8 kr[4], va0, va1, vb0, vb1;
  {
    int ktok = off + krow; if (ktok > qmax) ktok = qmax;
#pragma unroll
    for (int c = 0; c < 4; ++c)
      kr[c] = *(const s16x8*)(Kg + (size_t)ktok * 64 + kseg * 32 + c * 8);
    int va = off + 2 * vp, vb = va + 1;
    if (va > qmax) va = qmax;
    if (vb > qmax) vb = qmax;
    va0 = *(const s16x8*)(Vg + (size_t)va * 64 + vdc * 16);
    va1 = *(const s16x8*)(Vg + (size_t)va * 64 + vdc * 16 + 8);
    vb0 = *(const s16x8*)(Vg + (size_t)vb * 64 + vdc * 16);
    vb1 = *(const s16x8*)(Vg + (size_t)vb * 64 + vdc * 16 + 8);
  }

  for (int kt = 0; kt < len; kt += 64) {
    __syncthreads();                       // previous tile's compute done
#pragma unroll
    for (int c = 0; c < 4; ++c)
      *(s16x8*)&Klds[krow][kseg * 32 + c * 8] = kr[c];
#pragma unroll
    for (int j = 0; j < 8; ++j) {
      unsigned int p0 = (unsigned int)(unsigned short)va0[j] |
                        ((unsigned int)(unsigned short)vb0[j] << 16);
      unsigned int p1 = (unsigned int)(unsigned short)va1[j] |
                        ((unsigned int)(unsigned short)vb1[j] << 16);
      *(unsigned int*)&Vt[vdc * 16 + j][2 * vp]     = p0;
      *(unsigned int*)&Vt[vdc * 16 + 8 + j][2 * vp] = p1;
    }
    int ktn = kt + 64;
    if (ktn < len) {                       // prefetch next tile into regs
      int ktok = off + ktn + krow; if (ktok > qmax) ktok = qmax;
#pragma unroll
      for (int c = 0; c < 4; ++c)
        kr[c] = *(const s16x8*)(Kg + (size_t)ktok * 64 + kseg * 32 + c * 8);
      int va = off + ktn + 2 * vp, vb = va + 1;
      if (va > qmax) va = qmax;
      if (vb > qmax) vb = qmax;
      va0 = *(const s16x8*)(Vg + (size_t)va * 64 + vdc * 16);
      va1 = *(const s16x8*)(Vg + (size_t)va * 64 + vdc * 16 + 8);
      vb0 = *(const s16x8*)(Vg + (size_t)vb * 64 + vdc * 16);
      vb1 = *(const s16x8*)(Vg + (size_t)vb * 64 + vdc * 16 + 8);
    }
    __syncthreads();                       // LDS tile ready

    // ---- scores: S^T[key][q] for 64 keys x 32 q rows -------------------
    f32x4 s[2][4];
#pragma unroll
    for (int sub = 0; sub < 4; ++sub) {
      bf16x8 ka0 = *(const bf16x8*)(&Klds[sub * 16 + r][g * 8]);
      bf16x8 ka1 = *(const bf16x8*)(&Klds[sub * 16 + r][32 + g * 8]);
#pragma unroll
      for (int qi = 0; qi < 2; ++qi) {
        f32x4 acc = {};
        acc = mfma32(ka0, qf[qi][0], acc);
        acc = mfma32(ka1, qf[qi][1], acc);
        s[qi][sub] = acc;
      }
    }

    bool tail = (kt + 64 > len);
    s16x4 pf[2][4];
#pragma unroll
    for (int qi = 0; qi < 2; ++qi) {
      float sc[4][4];
      float tmax = -1e30f;
#pragma unroll
      for (int sub = 0; sub < 4; ++sub)
#pragma unroll
        for (int e = 0; e < 4; ++e) {
          float v = s[qi][sub][e] * SCALE_LOG2;
          sc[sub][e] = v;
          tmax = fmaxf(tmax, v);
        }
      if (tail) {
#pragma unroll
        for (int sub = 0; sub < 4; ++sub)
#pragma unroll
          for (int e = 0; e < 4; ++e)
            if (kt + sub * 16 + 4 * g + e >= len) sc[sub][e] = -1e30f;
        tmax = -1e30f;
#pragma unroll
        for (int sub = 0; sub < 4; ++sub)
#pragma unroll
          for (int e = 0; e < 4; ++e) tmax = fmaxf(tmax, sc[sub][e]);
      }
      tmax = fmaxf(tmax, __shfl_xor(tmax, 16));
      tmax = fmaxf(tmax, __shfl_xor(tmax, 32));
      float mq = m[qi];
      if (!__all(tmax <= mq + 8.f)) {      // defer-max (log2 domain)
        float mnew = fmaxf(mq, tmax);
        float alpha = exp2f(mq - mnew);
        lsum[qi] *= alpha;
        m[qi] = mnew; mq = mnew;
        float al[4];
#pragma unroll
        for (int e = 0; e < 4; ++e) al[e] = __shfl(alpha, 4 * g + e);
#pragma unroll
        for (int dt = 0; dt < 4; ++dt)
#pragma unroll
          for (int e = 0; e < 4; ++e) o[qi][dt][e] *= al[e];
      }
      float psum = 0.f;
#pragma unroll
      for (int sub = 0; sub < 4; ++sub) {
        float p[4];
        bf16x4 pb;
#pragma unroll
        for (int e = 0; e < 4; ++e) {
          p[e] = exp2f(sc[sub][e] - mq);
          psum += p[e];
          pb[e] = (__bf16)p[e];
        }
        pf[qi][sub] = __builtin_bit_cast(s16x4, pb);
      }
      psum += __shfl_xor(psum, 16);
      psum += __shfl_xor(psum, 32);
      lsum[qi] += psum;
    }

    // ---- PV: O += P * V  (V^T frags b64, reused across qi) --------------
#pragma unroll
    for (int dt = 0; dt < 4; ++dt)
#pragma unroll
      for (int sub = 0; sub < 4; ++sub) {
        s16x4 vf = *(const s16x4*)(&Vt[dt * 16 + r][sub * 16 + 4 * g]);
#pragma unroll
        for (int qi = 0; qi < 2; ++qi)
          o[qi][dt] = mfma16(pf[qi][sub], vf, o[qi][dt]);
      }
  }

#pragma unroll
  for (int qi = 0; qi < 2; ++qi) {
    float inv = 1.0f / lsum[qi];
    float il[4];
#pragma unroll
    for (int e = 0; e < 4; ++e) il[e] = __shfl(inv, 4 * g + e);
#pragma unroll
    for (int dt = 0; dt < 4; ++dt)
#pragma unroll
      for (int e = 0; e < 4; ++e) {
        int tl = q0 + wave * 32 + qi * 16 + 4 * g + e;
        if (tl < len)
          O[(size_t)(off + tl) * 1024 + h * 64 + dt * 16 + r] =
              f2bf(o[qi][dt][e] * il[e]);
      }
  }
}

// ---------------------------------------------------------------------------
extern "C" void kernel_launch(void* const* d_in, const int* in_sizes, int n_in,
                              void* d_out, int out_size, void* d_ws, size_t ws_size,
                              hipStream_t stream) {
  const float* x     = (const float*)d_in[0];
  const float* pos   = (const float*)d_in[1];
  const int*   boff  = (const int*)d_in[2];
  const float* gamma = (const float*)d_in[3];
  const float* beta  = (const float*)d_in[4];
  const float* wqkv  = (const float*)d_in[5];
  const float* wout  = (const float*)d_in[6];
  const float* freqs = (const float*)d_in[7];
  float* out = (float*)d_out;
  int N  = in_sizes[0] / 1024;   // 6144
  int Bn = in_sizes[2] - 1;      // 8

  char* ws = (char*)d_ws;
  unsigned short* wqkvT = (unsigned short*)ws;
  unsigned short* woutT = (unsigned short*)(ws + (size_t)3072 * 1024 * 2);
  unsigned short* QKV   = (unsigned short*)(ws + (size_t)3072 * 1024 * 2 +
                                            (size_t)1024 * 1024 * 2);
  size_t qkvBytes = (size_t)48 * N * 64 * 2;
  unsigned short* hbuf = (unsigned short*)((char*)QKV + qkvBytes);
  unsigned short* Obuf = hbuf;  // h is dead after the QKV GEMM

  ln_kernel<<<N / 4, 256, 0, stream>>>(x, gamma, beta, hbuf, N);
  transpose_bf16<<<dim3(3072 / 64, 1024 / 64), 256, 0, stream>>>(wqkv, wqkvT, 1024, 3072);
  transpose_bf16<<<dim3(1024 / 64, 1024 / 64), 256, 0, stream>>>(wout, woutT, 1024, 1024);
  gemm_bt<1><<<dim3(3072 / 128, N / 128), 256, 0, stream>>>(
      hbuf, wqkvT, nullptr, nullptr, QKV, N, 3072, 1024);
  rope_kernel<<<(N * 512) / 256, 256, 0, stream>>>(QKV, pos, freqs, N);
  attn_kernel<<<Bn * 16 * 16, 128, 0, stream>>>(QKV, boff, Obuf, N);
  gemm_bt<0><<<dim3(1024 / 128, N / 128), 256, 0, stream>>>(
      Obuf, woutT, x, out, nullptr, N, 1024, 1024);
}

// Round 6
// 189.721 us; speedup vs baseline: 1.4230x; 1.1430x over previous
//
#include <hip/hip_runtime.h>

// ---------------------------------------------------------------------------
// MultilevelSelfAttentionBlockWithRoPE on MI355X (gfx950)
// LN -> (W transpose->bf16) -> QKV GEMM (bf16 MFMA) -> RoPE -> flash
// attention -> out GEMM + residual.
// R6: identical to R5 except the attn block->XCD mapping.
// R5 post-mortem: old swizzle put ONE BATCH PER XCD (work ~ len^2 -> 1.68x
// max/mean XCD imbalance; short-batch XCDs idle -> occ 13%, attn 108us).
// New mapping: (b,h) pair -> XCD pair&7 (each XCD gets every batch exactly
// twice = balanced), 16 q-blocks of a pair consecutive on that XCD (K/V
// stays in its 4MB L2).  Assumes bid%8 = XCD (HK chiplet pattern).
// ---------------------------------------------------------------------------

typedef float  f32x4  __attribute__((ext_vector_type(4)));
typedef __bf16 bf16x8 __attribute__((ext_vector_type(8)));
typedef __bf16 bf16x4 __attribute__((ext_vector_type(4)));
typedef short  s16x4  __attribute__((ext_vector_type(4)));
typedef short  s16x8  __attribute__((ext_vector_type(8)));
typedef unsigned short u16x4 __attribute__((ext_vector_type(4)));

typedef __attribute__((address_space(1))) void as1_void_t;
typedef __attribute__((address_space(3))) void as3_void_t;

static __device__ __forceinline__ unsigned short f2bf(float f) {
  unsigned int u = __float_as_uint(f);
  u += 0x7fffu + ((u >> 16) & 1u);          // round-to-nearest-even
  return (unsigned short)(u >> 16);
}
static __device__ __forceinline__ float bf2f(unsigned short s) {
  return __uint_as_float(((unsigned int)s) << 16);
}

static __device__ __forceinline__ void gload_lds16(const void* g, void* l) {
  __builtin_amdgcn_global_load_lds((as1_void_t*)g, (as3_void_t*)l, 16, 0, 0);
}

static __device__ __forceinline__ f32x4 mfma32(bf16x8 a, bf16x8 b, f32x4 c) {
  return __builtin_amdgcn_mfma_f32_16x16x32_bf16(a, b, c, 0, 0, 0);
}
static __device__ __forceinline__ f32x4 mfma16(s16x4 a, s16x4 b, f32x4 c) {
  return __builtin_amdgcn_mfma_f32_16x16x16bf16_1k(a, b, c, 0, 0, 0);
}

// ---------------------------------------------------------------------------
// LayerNorm: x f32 [N][1024] -> h bf16 [N][1024].  One wave per row.
// ---------------------------------------------------------------------------
__global__ __launch_bounds__(256) void ln_kernel(
    const float* __restrict__ x, const float* __restrict__ gamma,
    const float* __restrict__ beta, unsigned short* __restrict__ h, int Ntok) {
  int row  = blockIdx.x * 4 + (threadIdx.x >> 6);
  int lane = threadIdx.x & 63;
  const float* xr = x + (size_t)row * 1024;
  f32x4 v[4];
  float s = 0.f, ss = 0.f;
#pragma unroll
  for (int c = 0; c < 4; ++c) {
    v[c] = *(const f32x4*)(xr + c * 256 + lane * 4);
#pragma unroll
    for (int j = 0; j < 4; ++j) { s += v[c][j]; ss += v[c][j] * v[c][j]; }
  }
#pragma unroll
  for (int d = 1; d < 64; d <<= 1) {
    s  += __shfl_xor(s, d);
    ss += __shfl_xor(ss, d);
  }
  float mu  = s * (1.f / 1024.f);
  float var = ss * (1.f / 1024.f) - mu * mu;
  float inv = rsqrtf(var + 1e-5f);
#pragma unroll
  for (int c = 0; c < 4; ++c) {
    f32x4 gv = *(const f32x4*)(gamma + c * 256 + lane * 4);
    f32x4 bv = *(const f32x4*)(beta  + c * 256 + lane * 4);
    u16x4 hv;
#pragma unroll
    for (int j = 0; j < 4; ++j) hv[j] = f2bf((v[c][j] - mu) * inv * gv[j] + bv[j]);
    *(u16x4*)(h + (size_t)row * 1024 + c * 256 + lane * 4) = hv;
  }
}

// ---------------------------------------------------------------------------
// Transpose+convert: in f32 [R][C] -> out bf16 [C][R]
// ---------------------------------------------------------------------------
__global__ __launch_bounds__(256) void transpose_bf16(
    const float* __restrict__ in, unsigned short* __restrict__ out, int R, int C) {
  __shared__ unsigned short tile[64][65];
  int c0 = blockIdx.x * 64, r0 = blockIdx.y * 64;
  int t = threadIdx.x;
  int tr = t >> 6, tc = t & 63;
#pragma unroll
  for (int i = 0; i < 16; ++i) {
    int rr = i * 4 + tr;
    tile[tc][rr] = f2bf(in[(size_t)(r0 + rr) * C + c0 + tc]);
  }
  __syncthreads();
#pragma unroll
  for (int i = 0; i < 16; ++i) {
    int cc = i * 4 + tr;
    out[(size_t)(c0 + cc) * R + r0 + tc] = tile[cc][tc];
  }
}

// ---------------------------------------------------------------------------
// GEMM  C[M][Ncols] = A[M][K](bf16) * Bt[Ncols][K](bf16)^T
// MODE 0: Cf = acc + residual (f32 out)
// MODE 1: scatter bf16 into QKV planes [3][16][M][64]
// ---------------------------------------------------------------------------
template <int MODE>
__global__ __launch_bounds__(256) void gemm_bt(
    const unsigned short* __restrict__ A, const unsigned short* __restrict__ Bt,
    const float* __restrict__ residual, float* __restrict__ Cf,
    unsigned short* __restrict__ Cqkv, int M, int Ncols, int K) {
  __shared__ unsigned short Alds[128 * 32];
  __shared__ unsigned short Blds[128 * 32];
  int n0 = blockIdx.x * 128, m0 = blockIdx.y * 128;
  int t = threadIdx.x, lane = t & 63, wave = t >> 6;
  int wr = wave >> 1, wc = wave & 1;
  int r = lane & 15, g = lane >> 4;
  f32x4 acc[4][4] = {};

  int srow = lane >> 2;
  int scol = (lane & 3) * 8;

  for (int k0 = 0; k0 < K; k0 += 32) {
    __syncthreads();
#pragma unroll
    for (int c = 0; c < 2; ++c) {
      int seg = wave * 2 + c;
      gload_lds16(A  + (size_t)(m0 + seg * 16 + srow) * K + k0 + scol,
                  Alds + seg * 16 * 32);
      gload_lds16(Bt + (size_t)(n0 + seg * 16 + srow) * K + k0 + scol,
                  Blds + seg * 16 * 32);
    }
    __syncthreads();
    bf16x8 a[4], b[4];
#pragma unroll
    for (int m = 0; m < 4; ++m)
      a[m] = *(const bf16x8*)(Alds + (wr * 64 + m * 16 + r) * 32 + g * 8);
#pragma unroll
    for (int n = 0; n < 4; ++n)
      b[n] = *(const bf16x8*)(Blds + (wc * 64 + n * 16 + r) * 32 + g * 8);
#pragma unroll
    for (int m = 0; m < 4; ++m)
#pragma unroll
      for (int n = 0; n < 4; ++n)
        acc[m][n] = mfma32(a[m], b[n], acc[m][n]);
  }

#pragma unroll
  for (int mi = 0; mi < 4; ++mi) {
    int grow0 = m0 + wr * 64 + mi * 16 + g * 4;
#pragma unroll
    for (int ni = 0; ni < 4; ++ni) {
      int gcol = n0 + wc * 64 + ni * 16 + r;
      f32x4 v = acc[mi][ni];
#pragma unroll
      for (int e = 0; e < 4; ++e) {
        int grow = grow0 + e;
        if (MODE == 0) {
          Cf[(size_t)grow * Ncols + gcol] =
              v[e] + residual[(size_t)grow * Ncols + gcol];
        } else {
          int which = gcol >> 10, rem = gcol & 1023, hh = rem >> 6, d = rem & 63;
          Cqkv[((size_t)(which * 16 + hh) * M + grow) * 64 + d] = f2bf(v[e]);
        }
      }
    }
  }
}

// ---------------------------------------------------------------------------
// RoPE in place on Q,K planes of QKV [3][16][N][64] bf16.
// ---------------------------------------------------------------------------
__global__ __launch_bounds__(256) void rope_kernel(
    unsigned short* __restrict__ QKV, const float* __restrict__ pos,
    const float* __restrict__ freqs, int Ntok) {
  int t = blockIdx.x * 256 + threadIdx.x;
  if (t >= Ntok * 512) return;
  int kk = t & 31, h = (t >> 5) & 15, i = t >> 9;
  float lvlf = pos[i * 3 + 0];
  float py   = pos[i * 3 + 1];
  float px   = pos[i * 3 + 2];
  int lvl = (int)lvlf;
  lvl = lvl < 0 ? 0 : (lvl > 3 ? 3 : lvl);
  const float* fp = freqs + (((lvl * 16 + h) * 32 + kk) << 1);
  float ang = fp[0] * py + fp[1] * px;
  float s, c;
  __sincosf(ang, &s, &c);
  size_t qoff = ((size_t)h * Ntok + i) * 64 + 2 * kk;
  size_t koff = qoff + (size_t)16 * Ntok * 64;
  unsigned int q2 = *(const unsigned int*)(QKV + qoff);
  float qa = bf2f((unsigned short)(q2 & 0xffff));
  float qb = bf2f((unsigned short)(q2 >> 16));
  *(unsigned int*)(QKV + qoff) =
      (unsigned int)f2bf(qa * c - qb * s) | ((unsigned int)f2bf(qa * s + qb * c) << 16);
  unsigned int k2 = *(const unsigned int*)(QKV + koff);
  float ka = bf2f((unsigned short)(k2 & 0xffff));
  float kb = bf2f((unsigned short)(k2 >> 16));
  *(unsigned int*)(QKV + koff) =
      (unsigned int)f2bf(ka * c - kb * s) | ((unsigned int)f2bf(ka * s + kb * c) << 16);
}

// ---------------------------------------------------------------------------
// Flash attention.  Block = (batch, head, 64 q rows); 2 waves x 32 q rows
// (2 qi of 16).  S^T = K*Q^T (mfma 16x16x32); per-64-key-tile online softmax
// (log2 domain, defer-max); V transposed in LDS (PV B-frags = ds_read_b64,
// reused across qi); reg-staged single-LDS-buffer pipeline; balanced
// XCD mapping: (b,h) pair -> XCD pair&7, q-blocks consecutive per pair.
// ---------------------------------------------------------------------------
__global__ __launch_bounds__(128, 3) void attn_kernel(
    const unsigned short* __restrict__ QKV, const int* __restrict__ boff,
    unsigned short* __restrict__ O, int Ntok) {
  __shared__ unsigned short Klds[64][72];
  __shared__ unsigned short Vt[64][72];   // Vt[d][key]
  const float SCALE_LOG2 = 0.125f * 1.44269504088896340736f;

  // balanced XCD mapping (grid = 2048 = 8 xcd * 16 pairs * 16 qblk)
  int bid = blockIdx.x;
  int x = bid & 7, i = bid >> 3;
  int qblk = i & 15;
  int p = x + 8 * (i >> 4);               // (b,h) pair, resident on XCD x
  int h = p & 15, b = p >> 4;
  int off = boff[b], len = boff[b + 1] - off;
  int q0 = qblk * 64;
  if (q0 >= len) return;
  int t = threadIdx.x, lane = t & 63, wave = t >> 6;
  int r = lane & 15, g = lane >> 4;
  const unsigned short* Qg = QKV + (size_t)h * Ntok * 64;
  const unsigned short* Kg = QKV + (size_t)(16 + h) * Ntok * 64;
  const unsigned short* Vg = QKV + (size_t)(32 + h) * Ntok * 64;
  int qmax = off + len - 1;

  bf16x8 qf[2][2];
#pragma unroll
  for (int qi = 0; qi < 2; ++qi) {
    int qtok = off + q0 + wave * 32 + qi * 16 + r;
    if (qtok > qmax) qtok = qmax;
#pragma unroll
    for (int c = 0; c < 2; ++c)
      qf[qi][c] = *(const bf16x8*)(Qg + (size_t)qtok * 64 + c * 32 + g * 8);
  }

  float m[2] = {-1e30f, -1e30f}, lsum[2] = {0.f, 0.f};
  f32x4 o[2][4] = {};

  // staging assignments (128 threads)
  int krow = t >> 1, kseg = t & 1;   // K: key=krow, shorts [kseg*32, +32)
  int vp = t & 31, vdc = t >> 5;     // V: keys 2vp,2vp+1, d = vdc*16..+15

  s16x8 kr[4], va0, va1, vb0, vb1;
  {
    int ktok = off + krow; if (ktok > qmax) ktok = qmax;
#pragma unroll
    for (int c = 0; c < 4; ++c)
      kr[c] = *(const s16x8*)(Kg + (size_t)ktok * 64 + kseg * 32 + c * 8);
    int va = off + 2 * vp, vb = va + 1;
    if (va > qmax) va = qmax;
    if (vb > qmax) vb = qmax;
    va0 = *(const s16x8*)(Vg + (size_t)va * 64 + vdc * 16);
    va1 = *(const s16x8*)(Vg + (size_t)va * 64 + vdc * 16 + 8);
    vb0 = *(const s16x8*)(Vg + (size_t)vb * 64 + vdc * 16);
    vb1 = *(const s16x8*)(Vg + (size_t)vb * 64 + vdc * 16 + 8);
  }

  for (int kt = 0; kt < len; kt += 64) {
    __syncthreads();                       // previous tile's compute done
#pragma unroll
    for (int c = 0; c < 4; ++c)
      *(s16x8*)&Klds[krow][kseg * 32 + c * 8] = kr[c];
#pragma unroll
    for (int j = 0; j < 8; ++j) {
      unsigned int p0 = (unsigned int)(unsigned short)va0[j] |
                        ((unsigned int)(unsigned short)vb0[j] << 16);
      unsigned int p1 = (unsigned int)(unsigned short)va1[j] |
                        ((unsigned int)(unsigned short)vb1[j] << 16);
      *(unsigned int*)&Vt[vdc * 16 + j][2 * vp]     = p0;
      *(unsigned int*)&Vt[vdc * 16 + 8 + j][2 * vp] = p1;
    }
    int ktn = kt + 64;
    if (ktn < len) {                       // prefetch next tile into regs
      int ktok = off + ktn + krow; if (ktok > qmax) ktok = qmax;
#pragma unroll
      for (int c = 0; c < 4; ++c)
        kr[c] = *(const s16x8*)(Kg + (size_t)ktok * 64 + kseg * 32 + c * 8);
      int va = off + ktn + 2 * vp, vb = va + 1;
      if (va > qmax) va = qmax;
      if (vb > qmax) vb = qmax;
      va0 = *(const s16x8*)(Vg + (size_t)va * 64 + vdc * 16);
      va1 = *(const s16x8*)(Vg + (size_t)va * 64 + vdc * 16 + 8);
      vb0 = *(const s16x8*)(Vg + (size_t)vb * 64 + vdc * 16);
      vb1 = *(const s16x8*)(Vg + (size_t)vb * 64 + vdc * 16 + 8);
    }
    __syncthreads();                       // LDS tile ready

    // ---- scores: S^T[key][q] for 64 keys x 32 q rows -------------------
    f32x4 s[2][4];
#pragma unroll
    for (int sub = 0; sub < 4; ++sub) {
      bf16x8 ka0 = *(const bf16x8*)(&Klds[sub * 16 + r][g * 8]);
      bf16x8 ka1 = *(const bf16x8*)(&Klds[sub * 16 + r][32 + g * 8]);
#pragma unroll
      for (int qi = 0; qi < 2; ++qi) {
        f32x4 acc = {};
        acc = mfma32(ka0, qf[qi][0], acc);
        acc = mfma32(ka1, qf[qi][1], acc);
        s[qi][sub] = acc;
      }
    }

    bool tail = (kt + 64 > len);
    s16x4 pf[2][4];
#pragma unroll
    for (int qi = 0; qi < 2; ++qi) {
      float sc[4][4];
      float tmax = -1e30f;
#pragma unroll
      for (int sub = 0; sub < 4; ++sub)
#pragma unroll
        for (int e = 0; e < 4; ++e) {
          float v = s[qi][sub][e] * SCALE_LOG2;
          sc[sub][e] = v;
          tmax = fmaxf(tmax, v);
        }
      if (tail) {
#pragma unroll
        for (int sub = 0; sub < 4; ++sub)
#pragma unroll
          for (int e = 0; e < 4; ++e)
            if (kt + sub * 16 + 4 * g + e >= len) sc[sub][e] = -1e30f;
        tmax = -1e30f;
#pragma unroll
        for (int sub = 0; sub < 4; ++sub)
#pragma unroll
          for (int e = 0; e < 4; ++e) tmax = fmaxf(tmax, sc[sub][e]);
      }
      tmax = fmaxf(tmax, __shfl_xor(tmax, 16));
      tmax = fmaxf(tmax, __shfl_xor(tmax, 32));
      float mq = m[qi];
      if (!__all(tmax <= mq + 8.f)) {      // defer-max (log2 domain)
        float mnew = fmaxf(mq, tmax);
        float alpha = exp2f(mq - mnew);
        lsum[qi] *= alpha;
        m[qi] = mnew; mq = mnew;
        float al[4];
#pragma unroll
        for (int e = 0; e < 4; ++e) al[e] = __shfl(alpha, 4 * g + e);
#pragma unroll
        for (int dt = 0; dt < 4; ++dt)
#pragma unroll
          for (int e = 0; e < 4; ++e) o[qi][dt][e] *= al[e];
      }
      float psum = 0.f;
#pragma unroll
      for (int sub = 0; sub < 4; ++sub) {
        float pv[4];
        bf16x4 pb;
#pragma unroll
        for (int e = 0; e < 4; ++e) {
          pv[e] = exp2f(sc[sub][e] - mq);
          psum += pv[e];
          pb[e] = (__bf16)pv[e];
        }
        pf[qi][sub] = __builtin_bit_cast(s16x4, pb);
      }
      psum += __shfl_xor(psum, 16);
      psum += __shfl_xor(psum, 32);
      lsum[qi] += psum;
    }

    // ---- PV: O += P * V  (V^T frags b64, reused across qi) --------------
#pragma unroll
    for (int dt = 0; dt < 4; ++dt)
#pragma unroll
      for (int sub = 0; sub < 4; ++sub) {
        s16x4 vf = *(const s16x4*)(&Vt[dt * 16 + r][sub * 16 + 4 * g]);
#pragma unroll
        for (int qi = 0; qi < 2; ++qi)
          o[qi][dt] = mfma16(pf[qi][sub], vf, o[qi][dt]);
      }
  }

#pragma unroll
  for (int qi = 0; qi < 2; ++qi) {
    float inv = 1.0f / lsum[qi];
    float il[4];
#pragma unroll
    for (int e = 0; e < 4; ++e) il[e] = __shfl(inv, 4 * g + e);
#pragma unroll
    for (int dt = 0; dt < 4; ++dt)
#pragma unroll
      for (int e = 0; e < 4; ++e) {
        int tl = q0 + wave * 32 + qi * 16 + 4 * g + e;
        if (tl < len)
          O[(size_t)(off + tl) * 1024 + h * 64 + dt * 16 + r] =
              f2bf(o[qi][dt][e] * il[e]);
      }
  }
}

// ---------------------------------------------------------------------------
extern "C" void kernel_launch(void* const* d_in, const int* in_sizes, int n_in,
                              void* d_out, int out_size, void* d_ws, size_t ws_size,
                              hipStream_t stream) {
  const float* x     = (const float*)d_in[0];
  const float* pos   = (const float*)d_in[1];
  const int*   boff  = (const int*)d_in[2];
  const float* gamma = (const float*)d_in[3];
  const float* beta  = (const float*)d_in[4];
  const float* wqkv  = (const float*)d_in[5];
  const float* wout  = (const float*)d_in[6];
  const float* freqs = (const float*)d_in[7];
  float* out = (float*)d_out;
  int N  = in_sizes[0] / 1024;   // 6144
  int Bn = in_sizes[2] - 1;      // 8

  char* ws = (char*)d_ws;
  unsigned short* wqkvT = (unsigned short*)ws;
  unsigned short* woutT = (unsigned short*)(ws + (size_t)3072 * 1024 * 2);
  unsigned short* QKV   = (unsigned short*)(ws + (size_t)3072 * 1024 * 2 +
                                            (size_t)1024 * 1024 * 2);
  size_t qkvBytes = (size_t)48 * N * 64 * 2;
  unsigned short* hbuf = (unsigned short*)((char*)QKV + qkvBytes);
  unsigned short* Obuf = hbuf;  // h is dead after the QKV GEMM

  ln_kernel<<<N / 4, 256, 0, stream>>>(x, gamma, beta, hbuf, N);
  transpose_bf16<<<dim3(3072 / 64, 1024 / 64), 256, 0, stream>>>(wqkv, wqkvT, 1024, 3072);
  transpose_bf16<<<dim3(1024 / 64, 1024 / 64), 256, 0, stream>>>(wout, woutT, 1024, 1024);
  gemm_bt<1><<<dim3(3072 / 128, N / 128), 256, 0, stream>>>(
      hbuf, wqkvT, nullptr, nullptr, QKV, N, 3072, 1024);
  rope_kernel<<<(N * 512) / 256, 256, 0, stream>>>(QKV, pos, freqs, N);
  attn_kernel<<<Bn * 16 * 16, 128, 0, stream>>>(QKV, boff, Obuf, N);
  gemm_bt<0><<<dim3(1024 / 128, N / 128), 256, 0, stream>>>(
      Obuf, woutT, x, out, nullptr, N, 1024, 1024);
}

// Round 7
// 189.469 us; speedup vs baseline: 1.4249x; 1.0013x over previous
//
#include <hip/hip_runtime.h>

// ---------------------------------------------------------------------------
// MultilevelSelfAttentionBlockWithRoPE on MI355X (gfx950)
// LN -> (W transpose->bf16) -> QKV GEMM (bf16 MFMA) -> RoPE -> flash
// attention -> out GEMM + residual.
// R7: attn softmax micro-opts (R6 counters: VALUBusy 42%, chain-exposed):
//  - scale folded into exp2 via FMA (kills 32 v_mul/tile, no precision loss)
//  - lazy cross-lane max: defer-max test on PER-LANE max; the 2 dependent
//    __shfl_xor run only on the rare rescale path
//  - s_setprio(1) around MFMA clusters (T5; attn regime per m191)
// ---------------------------------------------------------------------------

typedef float  f32x4  __attribute__((ext_vector_type(4)));
typedef __bf16 bf16x8 __attribute__((ext_vector_type(8)));
typedef __bf16 bf16x4 __attribute__((ext_vector_type(4)));
typedef short  s16x4  __attribute__((ext_vector_type(4)));
typedef short  s16x8  __attribute__((ext_vector_type(8)));
typedef unsigned short u16x4 __attribute__((ext_vector_type(4)));

typedef __attribute__((address_space(1))) void as1_void_t;
typedef __attribute__((address_space(3))) void as3_void_t;

static __device__ __forceinline__ unsigned short f2bf(float f) {
  unsigned int u = __float_as_uint(f);
  u += 0x7fffu + ((u >> 16) & 1u);          // round-to-nearest-even
  return (unsigned short)(u >> 16);
}
static __device__ __forceinline__ float bf2f(unsigned short s) {
  return __uint_as_float(((unsigned int)s) << 16);
}

static __device__ __forceinline__ void gload_lds16(const void* g, void* l) {
  __builtin_amdgcn_global_load_lds((as1_void_t*)g, (as3_void_t*)l, 16, 0, 0);
}

static __device__ __forceinline__ f32x4 mfma32(bf16x8 a, bf16x8 b, f32x4 c) {
  return __builtin_amdgcn_mfma_f32_16x16x32_bf16(a, b, c, 0, 0, 0);
}
static __device__ __forceinline__ f32x4 mfma16(s16x4 a, s16x4 b, f32x4 c) {
  return __builtin_amdgcn_mfma_f32_16x16x16bf16_1k(a, b, c, 0, 0, 0);
}

// ---------------------------------------------------------------------------
// LayerNorm: x f32 [N][1024] -> h bf16 [N][1024].  One wave per row.
// ---------------------------------------------------------------------------
__global__ __launch_bounds__(256) void ln_kernel(
    const float* __restrict__ x, const float* __restrict__ gamma,
    const float* __restrict__ beta, unsigned short* __restrict__ h, int Ntok) {
  int row  = blockIdx.x * 4 + (threadIdx.x >> 6);
  int lane = threadIdx.x & 63;
  const float* xr = x + (size_t)row * 1024;
  f32x4 v[4];
  float s = 0.f, ss = 0.f;
#pragma unroll
  for (int c = 0; c < 4; ++c) {
    v[c] = *(const f32x4*)(xr + c * 256 + lane * 4);
#pragma unroll
    for (int j = 0; j < 4; ++j) { s += v[c][j]; ss += v[c][j] * v[c][j]; }
  }
#pragma unroll
  for (int d = 1; d < 64; d <<= 1) {
    s  += __shfl_xor(s, d);
    ss += __shfl_xor(ss, d);
  }
  float mu  = s * (1.f / 1024.f);
  float var = ss * (1.f / 1024.f) - mu * mu;
  float inv = rsqrtf(var + 1e-5f);
#pragma unroll
  for (int c = 0; c < 4; ++c) {
    f32x4 gv = *(const f32x4*)(gamma + c * 256 + lane * 4);
    f32x4 bv = *(const f32x4*)(beta  + c * 256 + lane * 4);
    u16x4 hv;
#pragma unroll
    for (int j = 0; j < 4; ++j) hv[j] = f2bf((v[c][j] - mu) * inv * gv[j] + bv[j]);
    *(u16x4*)(h + (size_t)row * 1024 + c * 256 + lane * 4) = hv;
  }
}

// ---------------------------------------------------------------------------
// Transpose+convert: in f32 [R][C] -> out bf16 [C][R]
// ---------------------------------------------------------------------------
__global__ __launch_bounds__(256) void transpose_bf16(
    const float* __restrict__ in, unsigned short* __restrict__ out, int R, int C) {
  __shared__ unsigned short tile[64][65];
  int c0 = blockIdx.x * 64, r0 = blockIdx.y * 64;
  int t = threadIdx.x;
  int tr = t >> 6, tc = t & 63;
#pragma unroll
  for (int i = 0; i < 16; ++i) {
    int rr = i * 4 + tr;
    tile[tc][rr] = f2bf(in[(size_t)(r0 + rr) * C + c0 + tc]);
  }
  __syncthreads();
#pragma unroll
  for (int i = 0; i < 16; ++i) {
    int cc = i * 4 + tr;
    out[(size_t)(c0 + cc) * R + r0 + tc] = tile[cc][tc];
  }
}

// ---------------------------------------------------------------------------
// GEMM  C[M][Ncols] = A[M][K](bf16) * Bt[Ncols][K](bf16)^T
// MODE 0: Cf = acc + residual (f32 out)
// MODE 1: scatter bf16 into QKV planes [3][16][M][64]
// ---------------------------------------------------------------------------
template <int MODE>
__global__ __launch_bounds__(256) void gemm_bt(
    const unsigned short* __restrict__ A, const unsigned short* __restrict__ Bt,
    const float* __restrict__ residual, float* __restrict__ Cf,
    unsigned short* __restrict__ Cqkv, int M, int Ncols, int K) {
  __shared__ unsigned short Alds[128 * 32];
  __shared__ unsigned short Blds[128 * 32];
  int n0 = blockIdx.x * 128, m0 = blockIdx.y * 128;
  int t = threadIdx.x, lane = t & 63, wave = t >> 6;
  int wr = wave >> 1, wc = wave & 1;
  int r = lane & 15, g = lane >> 4;
  f32x4 acc[4][4] = {};

  int srow = lane >> 2;
  int scol = (lane & 3) * 8;

  for (int k0 = 0; k0 < K; k0 += 32) {
    __syncthreads();
#pragma unroll
    for (int c = 0; c < 2; ++c) {
      int seg = wave * 2 + c;
      gload_lds16(A  + (size_t)(m0 + seg * 16 + srow) * K + k0 + scol,
                  Alds + seg * 16 * 32);
      gload_lds16(Bt + (size_t)(n0 + seg * 16 + srow) * K + k0 + scol,
                  Blds + seg * 16 * 32);
    }
    __syncthreads();
    bf16x8 a[4], b[4];
#pragma unroll
    for (int m = 0; m < 4; ++m)
      a[m] = *(const bf16x8*)(Alds + (wr * 64 + m * 16 + r) * 32 + g * 8);
#pragma unroll
    for (int n = 0; n < 4; ++n)
      b[n] = *(const bf16x8*)(Blds + (wc * 64 + n * 16 + r) * 32 + g * 8);
#pragma unroll
    for (int m = 0; m < 4; ++m)
#pragma unroll
      for (int n = 0; n < 4; ++n)
        acc[m][n] = mfma32(a[m], b[n], acc[m][n]);
  }

#pragma unroll
  for (int mi = 0; mi < 4; ++mi) {
    int grow0 = m0 + wr * 64 + mi * 16 + g * 4;
#pragma unroll
    for (int ni = 0; ni < 4; ++ni) {
      int gcol = n0 + wc * 64 + ni * 16 + r;
      f32x4 v = acc[mi][ni];
#pragma unroll
      for (int e = 0; e < 4; ++e) {
        int grow = grow0 + e;
        if (MODE == 0) {
          Cf[(size_t)grow * Ncols + gcol] =
              v[e] + residual[(size_t)grow * Ncols + gcol];
        } else {
          int which = gcol >> 10, rem = gcol & 1023, hh = rem >> 6, d = rem & 63;
          Cqkv[((size_t)(which * 16 + hh) * M + grow) * 64 + d] = f2bf(v[e]);
        }
      }
    }
  }
}

// ---------------------------------------------------------------------------
// RoPE in place on Q,K planes of QKV [3][16][N][64] bf16.
// ---------------------------------------------------------------------------
__global__ __launch_bounds__(256) void rope_kernel(
    unsigned short* __restrict__ QKV, const float* __restrict__ pos,
    const float* __restrict__ freqs, int Ntok) {
  int t = blockIdx.x * 256 + threadIdx.x;
  if (t >= Ntok * 512) return;
  int kk = t & 31, h = (t >> 5) & 15, i = t >> 9;
  float lvlf = pos[i * 3 + 0];
  float py   = pos[i * 3 + 1];
  float px   = pos[i * 3 + 2];
  int lvl = (int)lvlf;
  lvl = lvl < 0 ? 0 : (lvl > 3 ? 3 : lvl);
  const float* fp = freqs + (((lvl * 16 + h) * 32 + kk) << 1);
  float ang = fp[0] * py + fp[1] * px;
  float s, c;
  __sincosf(ang, &s, &c);
  size_t qoff = ((size_t)h * Ntok + i) * 64 + 2 * kk;
  size_t koff = qoff + (size_t)16 * Ntok * 64;
  unsigned int q2 = *(const unsigned int*)(QKV + qoff);
  float qa = bf2f((unsigned short)(q2 & 0xffff));
  float qb = bf2f((unsigned short)(q2 >> 16));
  *(unsigned int*)(QKV + qoff) =
      (unsigned int)f2bf(qa * c - qb * s) | ((unsigned int)f2bf(qa * s + qb * c) << 16);
  unsigned int k2 = *(const unsigned int*)(QKV + koff);
  float ka = bf2f((unsigned short)(k2 & 0xffff));
  float kb = bf2f((unsigned short)(k2 >> 16));
  *(unsigned int*)(QKV + koff) =
      (unsigned int)f2bf(ka * c - kb * s) | ((unsigned int)f2bf(ka * s + kb * c) << 16);
}

// ---------------------------------------------------------------------------
// Flash attention.  Block = (batch, head, 64 q rows); 2 waves x 32 q rows
// (2 qi of 16).  S^T = K*Q^T (mfma 16x16x32); per-64-key-tile online softmax
// (log2 domain, lazy defer-max); V transposed in LDS (PV B-frags =
// ds_read_b64, reused across qi); reg-staged single-LDS-buffer pipeline;
// balanced XCD mapping: (b,h) pair -> XCD pair&7.
// ---------------------------------------------------------------------------
__global__ __launch_bounds__(128, 3) void attn_kernel(
    const unsigned short* __restrict__ QKV, const int* __restrict__ boff,
    unsigned short* __restrict__ O, int Ntok) {
  __shared__ unsigned short Klds[64][72];
  __shared__ unsigned short Vt[64][72];   // Vt[d][key]
  const float SCALE_LOG2 = 0.125f * 1.44269504088896340736f;

  // balanced XCD mapping (grid = 2048 = 8 xcd * 16 pairs * 16 qblk)
  int bid = blockIdx.x;
  int x = bid & 7, i = bid >> 3;
  int qblk = i & 15;
  int p = x + 8 * (i >> 4);               // (b,h) pair, resident on XCD x
  int h = p & 15, b = p >> 4;
  int off = boff[b], len = boff[b + 1] - off;
  int q0 = qblk * 64;
  if (q0 >= len) return;
  int t = threadIdx.x, lane = t & 63, wave = t >> 6;
  int r = lane & 15, g = lane >> 4;
  const unsigned short* Qg = QKV + (size_t)h * Ntok * 64;
  const unsigned short* Kg = QKV + (size_t)(16 + h) * Ntok * 64;
  const unsigned short* Vg = QKV + (size_t)(32 + h) * Ntok * 64;
  int qmax = off + len - 1;

  bf16x8 qf[2][2];
#pragma unroll
  for (int qi = 0; qi < 2; ++qi) {
    int qtok = off + q0 + wave * 32 + qi * 16 + r;
    if (qtok > qmax) qtok = qmax;
#pragma unroll
    for (int c = 0; c < 2; ++c)
      qf[qi][c] = *(const bf16x8*)(Qg + (size_t)qtok * 64 + c * 32 + g * 8);
  }

  float m[2] = {-1e30f, -1e30f}, lsum[2] = {0.f, 0.f};
  f32x4 o[2][4] = {};

  // staging assignments (128 threads)
  int krow = t >> 1, kseg = t & 1;   // K: key=krow, shorts [kseg*32, +32)
  int vp = t & 31, vdc = t >> 5;     // V: keys 2vp,2vp+1, d = vdc*16..+15

  s16x8 kr[4], va0, va1, vb0, vb1;
  {
    int ktok = off + krow; if (ktok > qmax) ktok = qmax;
#pragma unroll
    for (int c = 0; c < 4; ++c)
      kr[c] = *(const s16x8*)(Kg + (size_t)ktok * 64 + kseg * 32 + c * 8);
    int va = off + 2 * vp, vb = va + 1;
    if (va > qmax) va = qmax;
    if (vb > qmax) vb = qmax;
    va0 = *(const s16x8*)(Vg + (size_t)va * 64 + vdc * 16);
    va1 = *(const s16x8*)(Vg + (size_t)va * 64 + vdc * 16 + 8);
    vb0 = *(const s16x8*)(Vg + (size_t)vb * 64 + vdc * 16);
    vb1 = *(const s16x8*)(Vg + (size_t)vb * 64 + vdc * 16 + 8);
  }

  for (int kt = 0; kt < len; kt += 64) {
    __syncthreads();                       // previous tile's compute done
#pragma unroll
    for (int c = 0; c < 4; ++c)
      *(s16x8*)&Klds[krow][kseg * 32 + c * 8] = kr[c];
#pragma unroll
    for (int j = 0; j < 8; ++j) {
      unsigned int p0 = (unsigned int)(unsigned short)va0[j] |
                        ((unsigned int)(unsigned short)vb0[j] << 16);
      unsigned int p1 = (unsigned int)(unsigned short)va1[j] |
                        ((unsigned int)(unsigned short)vb1[j] << 16);
      *(unsigned int*)&Vt[vdc * 16 + j][2 * vp]     = p0;
      *(unsigned int*)&Vt[vdc * 16 + 8 + j][2 * vp] = p1;
    }
    int ktn = kt + 64;
    if (ktn < len) {                       // prefetch next tile into regs
      int ktok = off + ktn + krow; if (ktok > qmax) ktok = qmax;
#pragma unroll
      for (int c = 0; c < 4; ++c)
        kr[c] = *(const s16x8*)(Kg + (size_t)ktok * 64 + kseg * 32 + c * 8);
      int va = off + ktn + 2 * vp, vb = va + 1;
      if (va > qmax) va = qmax;
      if (vb > qmax) vb = qmax;
      va0 = *(const s16x8*)(Vg + (size_t)va * 64 + vdc * 16);
      va1 = *(const s16x8*)(Vg + (size_t)va * 64 + vdc * 16 + 8);
      vb0 = *(const s16x8*)(Vg + (size_t)vb * 64 + vdc * 16);
      vb1 = *(const s16x8*)(Vg + (size_t)vb * 64 + vdc * 16 + 8);
    }
    __syncthreads();                       // LDS tile ready

    // ---- scores: S^T[key][q] raw, 64 keys x 32 q rows -------------------
    f32x4 s[2][4];
    __builtin_amdgcn_s_setprio(1);
#pragma unroll
    for (int sub = 0; sub < 4; ++sub) {
      bf16x8 ka0 = *(const bf16x8*)(&Klds[sub * 16 + r][g * 8]);
      bf16x8 ka1 = *(const bf16x8*)(&Klds[sub * 16 + r][32 + g * 8]);
#pragma unroll
      for (int qi = 0; qi < 2; ++qi) {
        f32x4 acc = {};
        acc = mfma32(ka0, qf[qi][0], acc);
        acc = mfma32(ka1, qf[qi][1], acc);
        s[qi][sub] = acc;
      }
    }
    __builtin_amdgcn_s_setprio(0);

    bool tail = (kt + 64 > len);
    s16x4 pf[2][4];
#pragma unroll
    for (int qi = 0; qi < 2; ++qi) {
      float sc[4][4];                      // raw scores (masked)
      float tmax = -1e30f;                 // per-lane max, raw domain
#pragma unroll
      for (int sub = 0; sub < 4; ++sub)
#pragma unroll
        for (int e = 0; e < 4; ++e) {
          float v = s[qi][sub][e];
          if (tail && (kt + sub * 16 + 4 * g + e >= len)) v = -1e30f;
          sc[sub][e] = v;
          tmax = fmaxf(tmax, v);
        }
      float mq = m[qi];
      // lazy defer-max: per-lane check, no shuffles in the common case
      if (!__all(tmax * SCALE_LOG2 <= mq + 8.f)) {
        float tm = tmax * SCALE_LOG2;
        tm = fmaxf(tm, __shfl_xor(tm, 16));
        tm = fmaxf(tm, __shfl_xor(tm, 32));
        float mnew = fmaxf(mq, tm);
        float alpha = exp2f(mq - mnew);
        lsum[qi] *= alpha;
        m[qi] = mnew; mq = mnew;
        float al[4];
#pragma unroll
        for (int e = 0; e < 4; ++e) al[e] = __shfl(alpha, 4 * g + e);
#pragma unroll
        for (int dt = 0; dt < 4; ++dt)
#pragma unroll
          for (int e = 0; e < 4; ++e) o[qi][dt][e] *= al[e];
      }
      float psum = 0.f;
#pragma unroll
      for (int sub = 0; sub < 4; ++sub) {
        float pv[4];
        bf16x4 pb;
#pragma unroll
        for (int e = 0; e < 4; ++e) {
          pv[e] = exp2f(fmaf(sc[sub][e], SCALE_LOG2, -mq));  // scale folded
          psum += pv[e];
          pb[e] = (__bf16)pv[e];
        }
        pf[qi][sub] = __builtin_bit_cast(s16x4, pb);
      }
      psum += __shfl_xor(psum, 16);
      psum += __shfl_xor(psum, 32);
      lsum[qi] += psum;
    }

    // ---- PV: O += P * V  (V^T frags b64, reused across qi) --------------
    __builtin_amdgcn_s_setprio(1);
#pragma unroll
    for (int dt = 0; dt < 4; ++dt)
#pragma unroll
      for (int sub = 0; sub < 4; ++sub) {
        s16x4 vf = *(const s16x4*)(&Vt[dt * 16 + r][sub * 16 + 4 * g]);
#pragma unroll
        for (int qi = 0; qi < 2; ++qi)
          o[qi][dt] = mfma16(pf[qi][sub], vf, o[qi][dt]);
      }
    __builtin_amdgcn_s_setprio(0);
  }

#pragma unroll
  for (int qi = 0; qi < 2; ++qi) {
    float inv = 1.0f / lsum[qi];
    float il[4];
#pragma unroll
    for (int e = 0; e < 4; ++e) il[e] = __shfl(inv, 4 * g + e);
#pragma unroll
    for (int dt = 0; dt < 4; ++dt)
#pragma unroll
      for (int e = 0; e < 4; ++e) {
        int tl = q0 + wave * 32 + qi * 16 + 4 * g + e;
        if (tl < len)
          O[(size_t)(off + tl) * 1024 + h * 64 + dt * 16 + r] =
              f2bf(o[qi][dt][e] * il[e]);
      }
  }
}

// ---------------------------------------------------------------------------
extern "C" void kernel_launch(void* const* d_in, const int* in_sizes, int n_in,
                              void* d_out, int out_size, void* d_ws, size_t ws_size,
                              hipStream_t stream) {
  const float* x     = (const float*)d_in[0];
  const float* pos   = (const float*)d_in[1];
  const int*   boff  = (const int*)d_in[2];
  const float* gamma = (const float*)d_in[3];
  const float* beta  = (const float*)d_in[4];
  const float* wqkv  = (const float*)d_in[5];
  const float* wout  = (const float*)d_in[6];
  const float* freqs = (const float*)d_in[7];
  float* out = (float*)d_out;
  int N  = in_sizes[0] / 1024;   // 6144
  int Bn = in_sizes[2] - 1;      // 8

  char* ws = (char*)d_ws;
  unsigned short* wqkvT = (unsigned short*)ws;
  unsigned short* woutT = (unsigned short*)(ws + (size_t)3072 * 1024 * 2);
  unsigned short* QKV   = (unsigned short*)(ws + (size_t)3072 * 1024 * 2 +
                                            (size_t)1024 * 1024 * 2);
  size_t qkvBytes = (size_t)48 * N * 64 * 2;
  unsigned short* hbuf = (unsigned short*)((char*)QKV + qkvBytes);
  unsigned short* Obuf = hbuf;  // h is dead after the QKV GEMM

  ln_kernel<<<N / 4, 256, 0, stream>>>(x, gamma, beta, hbuf, N);
  transpose_bf16<<<dim3(3072 / 64, 1024 / 64), 256, 0, stream>>>(wqkv, wqkvT, 1024, 3072);
  transpose_bf16<<<dim3(1024 / 64, 1024 / 64), 256, 0, stream>>>(wout, woutT, 1024, 1024);
  gemm_bt<1><<<dim3(3072 / 128, N / 128), 256, 0, stream>>>(
      hbuf, wqkvT, nullptr, nullptr, QKV, N, 3072, 1024);
  rope_kernel<<<(N * 512) / 256, 256, 0, stream>>>(QKV, pos, freqs, N);
  attn_kernel<<<Bn * 16 * 16, 128, 0, stream>>>(QKV, boff, Obuf, N);
  gemm_bt<0><<<dim3(1024 / 128, N / 128), 256, 0, stream>>>(
      Obuf, woutT, x, out, nullptr, N, 1024, 1024);
}